// Round 17
// baseline (578.743 us; speedup 1.0000x reference)
//
#include <hip/hip_runtime.h>
#include <math.h>

#define TOK_N   4096
#define DMODEL  1024
#define NEXP    8
#define DFFD    4096
#define CAPMAX  1024

typedef __bf16 bf16x8 __attribute__((ext_vector_type(8)));
typedef __bf16 bf16x4 __attribute__((ext_vector_type(4)));
typedef float  f32x4  __attribute__((ext_vector_type(4)));

__device__ __forceinline__ f32x4 MFMA16(bf16x8 a, bf16x8 b, f32x4 c){
  return __builtin_amdgcn_mfma_f32_16x16x32_bf16(a, b, c, 0, 0, 0);
}

__device__ __forceinline__ void gl16(const __bf16* g, __bf16* l){
  __builtin_amdgcn_global_load_lds(
      (const __attribute__((address_space(1))) unsigned int*)g,
      (__attribute__((address_space(3))) unsigned int*)l, 16, 0, 0);
}

__device__ __forceinline__ float wave_sum(float x){
  #pragma unroll
  for (int o=32;o;o>>=1) x += __shfl_down(x,o);
  return x;
}

// -------- prep: tconv4 (wq/wk/wv/wproj -> wAllT split) + LN1 in one dispatch --------
__global__ __launch_bounds__(256) void prep_kernel(
    const float* __restrict__ wq, const float* __restrict__ wk,
    const float* __restrict__ wv, const float* __restrict__ wp,
    __bf16* __restrict__ dh, __bf16* __restrict__ dl,
    const float* __restrict__ x, const float* __restrict__ g1,
    const float* __restrict__ b1, __bf16* __restrict__ hh, __bf16* __restrict__ hl)
{
  __shared__ float smem[64*65];
  int b = blockIdx.x, t = threadIdx.x;
  if (b < 1024){
    int z = b >> 8, rem = b & 255;
    int k0 = (rem >> 4) * 64, n0 = (rem & 15) * 64;
    const float* in = z==0?wq: z==1?wk: z==2?wv: wp;
    __bf16* oh = dh + (size_t)z*DMODEL*DMODEL;
    __bf16* ol = dl + (size_t)z*DMODEL*DMODEL;
    float (*tile)[65] = (float(*)[65])smem;
    #pragma unroll
    for (int i=0;i<4;i++){
      int row = (t>>4) + i*16, col = (t&15)*4;
      f32x4 f = __builtin_nontemporal_load((const f32x4*)&in[(size_t)(k0+row)*DMODEL + n0 + col]);
      tile[row][col]=f[0]; tile[row][col+1]=f[1]; tile[row][col+2]=f[2]; tile[row][col+3]=f[3];
    }
    __syncthreads();
    #pragma unroll
    for (int i=0;i<2;i++){
      int c = t + i*256;
      int orow = c>>3, kg = (c&7)*8;
      bf16x8 hv, lv;
      #pragma unroll
      for (int u=0;u<8;u++){
        float xv = tile[kg+u][orow];
        __bf16 hb = (__bf16)xv;
        hv[u]=hb; lv[u]=(__bf16)(xv-(float)hb);
      }
      *(bf16x8*)&oh[(size_t)(n0+orow)*DMODEL + k0 + kg] = hv;
      *(bf16x8*)&ol[(size_t)(n0+orow)*DMODEL + k0 + kg] = lv;
    }
  } else {
    int n = b - 1024;
    float4 v = ((const float4*)(x + (size_t)n*DMODEL))[t];
    float s  = v.x+v.y+v.z+v.w;
    float sq = v.x*v.x+v.y*v.y+v.z*v.z+v.w*v.w;
    s = wave_sum(s); sq = wave_sum(sq);
    int lane = t & 63, wid = t >> 6;
    if (lane==0){ smem[wid]=s; smem[8+wid]=sq; }
    __syncthreads();
    if (t==0){
      float a = smem[0]+smem[1]+smem[2]+smem[3];
      float c = smem[8]+smem[9]+smem[10]+smem[11];
      float mean = a*(1.0f/DMODEL);
      float var  = c*(1.0f/DMODEL) - mean*mean;
      smem[16] = mean; smem[17] = 1.0f/sqrtf(var + 1e-5f);
    }
    __syncthreads();
    float mean = smem[16], rstd = smem[17];
    float4 g4 = ((const float4*)g1)[t];
    float4 b4 = ((const float4*)b1)[t];
    float o_[4];
    o_[0] = (v.x-mean)*rstd*g4.x + b4.x;
    o_[1] = (v.y-mean)*rstd*g4.y + b4.y;
    o_[2] = (v.z-mean)*rstd*g4.z + b4.z;
    o_[3] = (v.w-mean)*rstd*g4.w + b4.w;
    bf16x4 h4, l4;
    #pragma unroll
    for (int i=0;i<4;i++){ __bf16 hb=(__bf16)o_[i]; h4[i]=hb; l4[i]=(__bf16)(o_[i]-(float)hb); }
    *(bf16x4*)&hh[(size_t)n*DMODEL + t*4] = h4;
    *(bf16x4*)&hl[(size_t)n*DMODEL + t*4] = l4;
  }
}

// -------- proj-epilogue + LN2 + router + out-init fused --------
__global__ __launch_bounds__(256) void ln_router_kernel(
    const float* __restrict__ p0, const float* __restrict__ p1,
    const float* __restrict__ xres, const float* __restrict__ bproj,
    const float* __restrict__ g, const float* __restrict__ b,
    __bf16* __restrict__ oh, __bf16* __restrict__ ol, float* __restrict__ out,
    const float* __restrict__ wr, const float* __restrict__ br,
    const float* __restrict__ wn, const float* __restrict__ bn,
    const float* __restrict__ wsk, const float* __restrict__ bsk,
    const float* __restrict__ noise,
    int* __restrict__ idx2, float* __restrict__ gate2, int* __restrict__ nskv)
{
  int n = blockIdx.x, t = threadIdx.x;
  size_t ro = (size_t)n*DMODEL/4 + t;
  float4 a  = ((const float4*)p0)[ro];
  float4 a1 = ((const float4*)p1)[ro];
  float4 xr = ((const float4*)xres)[ro];
  float4 bp = ((const float4*)bproj)[t];
  float4 v;
  v.x = a.x+a1.x+xr.x+bp.x; v.y = a.y+a1.y+xr.y+bp.y;
  v.z = a.z+a1.z+xr.z+bp.z; v.w = a.w+a1.w+xr.w+bp.w;
  float s  = v.x+v.y+v.z+v.w;
  float sq = v.x*v.x+v.y*v.y+v.z*v.z+v.w*v.w;
  s = wave_sum(s); sq = wave_sum(sq);
  __shared__ float r1[4], r2[4];
  __shared__ float mean_s, rstd_s, sk_s;
  int lane = t & 63, wid = t >> 6;
  if (lane==0){ r1[wid]=s; r2[wid]=sq; }
  __syncthreads();
  if (t==0){
    float aa = r1[0]+r1[1]+r1[2]+r1[3];
    float cc = r2[0]+r2[1]+r2[2]+r2[3];
    float mean = aa*(1.0f/DMODEL);
    float var  = cc*(1.0f/DMODEL) - mean*mean;
    mean_s = mean; rstd_s = 1.0f/sqrtf(var + 1e-5f);
  }
  __syncthreads();
  float mean = mean_s, rstd = rstd_s;
  float4 g4 = ((const float4*)g)[t];
  float4 b4 = ((const float4*)b)[t];
  float o_[4];
  o_[0] = (v.x-mean)*rstd*g4.x + b4.x;
  o_[1] = (v.y-mean)*rstd*g4.y + b4.y;
  o_[2] = (v.z-mean)*rstd*g4.z + b4.z;
  o_[3] = (v.w-mean)*rstd*g4.w + b4.w;
  bf16x4 h4, l4;
  #pragma unroll
  for (int i=0;i<4;i++){ __bf16 hb=(__bf16)o_[i]; h4[i]=hb; l4[i]=(__bf16)(o_[i]-(float)hb); }
  *(bf16x4*)&oh[(size_t)n*DMODEL + t*4] = h4;
  *(bf16x4*)&ol[(size_t)n*DMODEL + t*4] = l4;
  // router on exact f32 h2
  int d0 = t*4;
  const float* wrp = wr + (size_t)d0*NEXP;
  const float* wnp = wn + (size_t)d0*NEXP;
  const float* wsp = wsk + d0;
  float vals[17];
  #pragma unroll
  for (int i=0;i<17;i++) vals[i]=0.f;
  #pragma unroll
  for (int i=0;i<4;i++){
    #pragma unroll
    for (int e=0;e<NEXP;e++){
      vals[e]   += o_[i]*wrp[i*NEXP+e];
      vals[8+e] += o_[i]*wnp[i*NEXP+e];
    }
    vals[16] += o_[i]*wsp[i];
  }
  __shared__ float red[4][17];
  #pragma unroll
  for (int i=0;i<17;i++){
    float xx = wave_sum(vals[i]);
    if (lane==0) red[wid][i] = xx;
  }
  __syncthreads();
  if (t==0){
    float noisy[NEXP];
    #pragma unroll
    for (int e=0;e<NEXP;e++){
      float lr = red[0][e]+red[1][e]+red[2][e]+red[3][e] + br[e];
      float pn = red[0][8+e]+red[1][8+e]+red[2][8+e]+red[3][8+e] + bn[e];
      float sp = fmaxf(pn,0.f) + log1pf(expf(-fabsf(pn)));
      noisy[e] = lr + noise[(size_t)n*NEXP + e]*sp;
    }
    float sk = red[0][16]+red[1][16]+red[2][16]+red[3][16] + bsk[0];
    sk_s = sk;
    nskv[n] = (sk <= 0.f) ? 1 : 0;
    int i0=0; float v0=noisy[0];
    #pragma unroll
    for (int e=1;e<NEXP;e++) if (noisy[e] > v0){ v0=noisy[e]; i0=e; }
    int i1=-1; float v1=-INFINITY;
    #pragma unroll
    for (int e=0;e<NEXP;e++) if (e!=i0 && noisy[e] > v1){ v1=noisy[e]; i1=e; }
    float tt = expf(v1 - v0);
    idx2[n*2+0]=i0; idx2[n*2+1]=i1;
    gate2[n*2+0]=1.0f/(1.0f+tt); gate2[n*2+1]=tt/(1.0f+tt);
  }
  __syncthreads();
  if (sk_s > 0.f){
    v.x += o_[0]; v.y += o_[1]; v.z += o_[2]; v.w += o_[3];
  }
  ((float4*)out)[ro] = v;
}

// -------- group expert weight transpose-convert (NT both sides) --------
__global__ __launch_bounds__(256) void tconv_group(
    const float* __restrict__ ew1, const float* __restrict__ ew2,
    __bf16* __restrict__ e1T, __bf16* __restrict__ e2T, int e0, int G)
{
  __shared__ float tile[64][65];
  int z = blockIdx.z, t = threadIdx.x;
  const float* in; __bf16* out; int K, N, k0, n0;
  if (z < G){
    in = ew1 + (size_t)(e0+z)*DMODEL*DFFD; out = e1T + (size_t)z*DFFD*DMODEL;
    K = DMODEL; N = DFFD; k0 = blockIdx.y*64; n0 = blockIdx.x*64;
  } else {
    in = ew2 + (size_t)(e0+z-G)*DFFD*DMODEL; out = e2T + (size_t)(z-G)*DMODEL*DFFD;
    K = DFFD; N = DMODEL; k0 = blockIdx.x*64; n0 = blockIdx.y*64;
  }
  #pragma unroll
  for (int i=0;i<4;i++){
    int row = (t>>4) + i*16, col = (t&15)*4;
    f32x4 f = __builtin_nontemporal_load((const f32x4*)&in[(size_t)(k0+row)*N + n0 + col]);
    tile[row][col]=f[0]; tile[row][col+1]=f[1]; tile[row][col+2]=f[2]; tile[row][col+3]=f[3];
  }
  __syncthreads();
  #pragma unroll
  for (int i=0;i<2;i++){
    int c = t + i*256;
    int orow = c>>3, kg = (c&7)*8;
    bf16x8 hv;
    #pragma unroll
    for (int u=0;u<8;u++) hv[u] = (__bf16)tile[kg+u][orow];
    __builtin_nontemporal_store(hv, (bf16x8*)&out[(size_t)(n0+orow)*K + k0 + kg]);
  }
}

// ------- bf16-pair transpose: qkv v-slice -> vT[1024][4096] -------
__global__ __launch_bounds__(256) void btrans_kernel(
    const __bf16* __restrict__ ih, const __bf16* __restrict__ il, int istride, int icol0,
    __bf16* __restrict__ oh, __bf16* __restrict__ ol){
  __shared__ __bf16 th[64][72], tl[64][72];
  int r0 = blockIdx.x*64, c0 = blockIdx.y*64;
  int t = threadIdx.x;
  {
    int r = t>>2, cg = (t&3)*16;
    size_t go = (size_t)(r0+r)*istride + icol0 + c0 + cg;
    *(bf16x8*)&th[r][cg]   = *(const bf16x8*)&ih[go];
    *(bf16x8*)&th[r][cg+8] = *(const bf16x8*)&ih[go+8];
    *(bf16x8*)&tl[r][cg]   = *(const bf16x8*)&il[go];
    *(bf16x8*)&tl[r][cg+8] = *(const bf16x8*)&il[go+8];
  }
  __syncthreads();
  {
    int c = t>>2, rg = (t&3)*16;
    bf16x8 a,b,e,f;
    #pragma unroll
    for (int u=0;u<8;u++){ a[u]=th[rg+u][c]; b[u]=th[rg+8+u][c]; e[u]=tl[rg+u][c]; f[u]=tl[rg+8+u][c]; }
    size_t go = (size_t)(c0+c)*TOK_N + r0 + rg;
    *(bf16x8*)&oh[go]   = a;
    *(bf16x8*)&oh[go+8] = b;
    *(bf16x8*)&ol[go]   = e;
    *(bf16x8*)&ol[go+8] = f;
  }
}

// ---------------- MFMA GEMM, 128x128, BK=32, counted-vmcnt pipeline (T3/T4) ----------------
// + XCD-aware bijective block swizzle (T1): contiguous grid chunk per XCD.
// MODE 0: QKV  -> Ch/Cl hi/lo bf16 (N=3072)
// MODE 2: UP   -> Ch = bf16(relu(acc+bias)); A gathered via tok; z = expert-in-group
// MODE 4: DOWN -> Cf partial; z = (group-expert<<2)|kchunk, K=1024
// MODE 5: PROJK-> Cf partial; z = K-chunk of 512
template<int MODE, bool SPLIT>
__global__ __launch_bounds__(256) void mgemm(
    const __bf16* __restrict__ Ah, const __bf16* __restrict__ Al, int Astride,
    const __bf16* __restrict__ Bh, const __bf16* __restrict__ Bl, int Bstride,
    const float* __restrict__ bias,
    float* __restrict__ Cf, __bf16* __restrict__ Ch, __bf16* __restrict__ Cl,
    int N, int K,
    const int* __restrict__ tok, const __bf16* __restrict__ zbuf)
{
  if constexpr (MODE==2){
    int z = blockIdx.z;
    Bh  += (size_t)z*((size_t)DFFD*DMODEL);
    bias+= (size_t)z*DFFD;
    Ch  += (size_t)z*((size_t)CAPMAX*DFFD);
    tok += z*CAPMAX;
  }
  if constexpr (MODE==4){
    int ge = blockIdx.z>>2, kz = blockIdx.z&3;
    Ah  += (size_t)ge*((size_t)CAPMAX*DFFD) + kz*1024;
    Bh  += (size_t)ge*((size_t)DMODEL*DFFD) + kz*1024;
    Cf  += (size_t)blockIdx.z*((size_t)CAPMAX*DMODEL);
    tok += ge*CAPMAX;
  }
  if constexpr (MODE==5){
    int kz = blockIdx.z;
    Ah += kz*512; Al += kz*512; Bh += kz*512; Bl += kz*512;
    Cf += (size_t)kz*((size_t)TOK_N*DMODEL);
  }
  // XCD-aware swizzle: all grids have (gridX*gridY) % 8 == 0 -> bijective
  int bx, by;
  {
    int gx = gridDim.x;
    int wg = blockIdx.y*gx + blockIdx.x;
    int chunk = (gx*gridDim.y) >> 3;
    int swz = (wg & 7)*chunk + (wg >> 3);
    bx = swz % gx; by = swz / gx;
  }
  int m0 = by*128, n0 = bx*128;
  if ((MODE==2||MODE==4) && tok[m0] >= TOK_N) return;   // valid slots are a prefix (before any barrier)
  __shared__ __align__(16) __bf16 sAh[2*128*32], sBh[2*128*32];
  __shared__ __align__(16) __bf16 sAl[SPLIT?2*128*32:8], sBl[SPLIT?2*128*32:8];
  int t = threadIdx.x, lane = t&63, w = t>>6;
  int wr = w>>1, wc = w&1, fr = lane&15, kb = lane>>4;

  const __bf16* aB[2]; const __bf16* aBl[2]; bool aval[2];
  const __bf16* bB[2]; const __bf16* bBl[2];
  #pragma unroll
  for (int j=0;j<2;j++){
    int c = j*256 + w*64 + lane;
    int row = c>>2, grp = c&3;
    int sg = grp ^ ((row>>1)&3);           // pre-swizzled source chunk (involution)
    if (MODE==2){
      int token = tok[m0+row];
      if (token < TOK_N){ aB[j] = Ah + (size_t)token*Astride + sg*8; aval[j]=true; }
      else              { aB[j] = zbuf + sg*8;                       aval[j]=false; }
    } else {
      aB[j] = Ah + (size_t)(m0+row)*Astride + sg*8; aval[j]=true;
      if (SPLIT) aBl[j] = Al + (size_t)(m0+row)*Astride + sg*8;
    }
    bB[j] = Bh + (size_t)(n0+row)*Bstride + sg*8;
    if (SPLIT) bBl[j] = Bl + (size_t)(n0+row)*Bstride + sg*8;
  }

  auto stage = [&](int buf, int kt){       // SPLIT: 8 vmem ops/wave; else 4
    int base = buf*(128*32);
    #pragma unroll
    for (int j=0;j<2;j++){
      int cb8 = base + (j*256 + w*64)*8;
      gl16(aB[j] + (aval[j]? kt : 0), &sAh[cb8]);
      gl16(bB[j] + kt, &sBh[cb8]);
      if constexpr (SPLIT){
        gl16(aBl[j] + kt, &sAl[cb8]);
        gl16(bBl[j] + kt, &sBl[cb8]);
      }
    }
  };

  f32x4 acc[4][4];
  #pragma unroll
  for (int mt=0;mt<4;mt++)
    #pragma unroll
    for (int nt=0;nt<4;nt++) acc[mt][nt] = (f32x4){0.f,0.f,0.f,0.f};

  int nk = K >> 5;
  stage(0, 0);
  stage(1, 32);                            // all shapes have nk >= 2
  int xk = (kb ^ ((fr>>1)&3))*8;           // swizzled read slot within row
  for (int ik=0; ik<nk; ik++){
    int cur = ik & 1;
    if (ik+1 < nk){
      if constexpr (SPLIT) asm volatile("s_waitcnt vmcnt(8)" ::: "memory");
      else                 asm volatile("s_waitcnt vmcnt(4)" ::: "memory");
    } else {
      asm volatile("s_waitcnt vmcnt(0)" ::: "memory");
    }
    __builtin_amdgcn_s_barrier();          // every wave has its cur-buffer complete
    int fb = cur*(128*32);
    bf16x8 aFh[4], bFh[4];
    bf16x8 aFl[SPLIT?4:1], bFl[SPLIT?4:1];
    #pragma unroll
    for (int mt=0;mt<4;mt++) aFh[mt] = *(const bf16x8*)&sAh[fb + (wr*64+mt*16+fr)*32 + xk];
    #pragma unroll
    for (int nt=0;nt<4;nt++) bFh[nt] = *(const bf16x8*)&sBh[fb + (wc*64+nt*16+fr)*32 + xk];
    if constexpr (SPLIT){
      #pragma unroll
      for (int mt=0;mt<4;mt++) aFl[mt] = *(const bf16x8*)&sAl[fb + (wr*64+mt*16+fr)*32 + xk];
      #pragma unroll
      for (int nt=0;nt<4;nt++) bFl[nt] = *(const bf16x8*)&sBl[fb + (wc*64+nt*16+fr)*32 + xk];
    }
    asm volatile("s_waitcnt lgkmcnt(0)" ::: "memory");   // frags landed in regs
    __builtin_amdgcn_sched_barrier(0);                    // rule #18 fence
    __builtin_amdgcn_s_barrier();          // no wave still reading buf[cur]
    if (ik+2 < nk) stage(cur, (ik+2)<<5);  // refill cur; flies under MFMA + next step
    __builtin_amdgcn_s_setprio(1);
    #pragma unroll
    for (int mt=0;mt<4;mt++)
      #pragma unroll
      for (int nt=0;nt<4;nt++)
        acc[mt][nt] = MFMA16(aFh[mt], bFh[nt], acc[mt][nt]);
    if constexpr (SPLIT){
      #pragma unroll
      for (int mt=0;mt<4;mt++)
        #pragma unroll
        for (int nt=0;nt<4;nt++){
          acc[mt][nt] = MFMA16(aFh[mt], bFl[nt], acc[mt][nt]);
          acc[mt][nt] = MFMA16(aFl[mt], bFh[nt], acc[mt][nt]);
        }
    }
    __builtin_amdgcn_s_setprio(0);
  }

  #pragma unroll
  for (int mt=0; mt<4; mt++){
    int r0 = m0 + wr*64 + mt*16 + (lane>>4)*4;
    #pragma unroll
    for (int nt=0; nt<4; nt++){
      int col = n0 + wc*64 + nt*16 + fr;
      f32x4 v = acc[mt][nt];
      if constexpr (MODE==0){
        #pragma unroll
        for (int jj=0;jj<4;jj++){
          float val = v[jj];
          __bf16 hb = (__bf16)val;
          size_t idx = (size_t)(r0+jj)*N + col;
          Ch[idx] = hb; Cl[idx] = (__bf16)(val-(float)hb);
        }
      } else if constexpr (MODE==2){
        float bs = bias[col];
        #pragma unroll
        for (int jj=0;jj<4;jj++)
          Ch[(size_t)(r0+jj)*N + col] = (__bf16)fmaxf(v[jj]+bs, 0.f);
      } else {  // MODE 4 / 5: raw partial (cached — consumer reads it next)
        #pragma unroll
        for (int jj=0;jj<4;jj++)
          Cf[(size_t)(r0+jj)*N + col] = v[jj];
      }
    }
  }
}

// ------- per-token gather (race-free): out[n] += sum over this group's picks -------
__global__ __launch_bounds__(256) void gather_kernel(const float* __restrict__ yk,
    const int* __restrict__ tsrc, const float* __restrict__ gselb,
    const float* __restrict__ eb2, int e0, int G, float* __restrict__ out)
{
  int n = blockIdx.x, t = threadIdx.x;
  int s0 = tsrc[n*2], s1 = tsrc[n*2+1];
  float4 o; bool any = false;
  #pragma unroll
  for (int kk=0; kk<2; kk++){
    int src = kk ? s1 : s0;
    if (src < 0) continue;
    int e = src >> 10;
    int ge = e - e0;
    if (ge < 0 || ge >= G) continue;
    int r = src & (CAPMAX-1);
    if (!any){ o = ((const float4*)(out + (size_t)n*DMODEL))[t]; any = true; }
    float g = gselb[src];
    float4 acc = ((const float4*)(eb2 + (size_t)e*DMODEL))[t];
    #pragma unroll
    for (int z=0; z<4; z++){
      float4 p = ((const float4*)(yk + ((size_t)(ge*4+z)*CAPMAX + r)*DMODEL))[t];
      acc.x+=p.x; acc.y+=p.y; acc.z+=p.z; acc.w+=p.w;
    }
    o.x += g*acc.x; o.y += g*acc.y; o.z += g*acc.z; o.w += g*acc.w;
  }
  if (any) ((float4*)(out + (size_t)n*DMODEL))[t] = o;
}

// ---------------- MFMA causal flash attention, split-bf16, swapped operands ----------------
// Each block owns TWO q-tiles (qtA=blk, qtB=blk+8) of one (b,h): K/V staging shared.
__global__ __launch_bounds__(256) void attn_mfma_kernel(
    const __bf16* __restrict__ qkvh, const __bf16* __restrict__ qkvl,
    const __bf16* __restrict__ vth, const __bf16* __restrict__ vtl,
    __bf16* __restrict__ oh, __bf16* __restrict__ ol)
{
  __shared__ __align__(16) __bf16 Kh[2][64*64], Kl[2][64*64], Vh[2][64*64], Vl[2][64*64];
  __shared__ __align__(16) __bf16 Pt[2][4][16*64];
  int qtA = blockIdx.x, qtB = qtA + 8;
  int bh = blockIdx.y;
  int batch = bh>>4, head = bh&15;
  int t = threadIdx.x, lane = t&63, w = t>>6;
  int g = lane>>4, fr = lane&15;
  int col0 = head*64;
  size_t qbaseA = (size_t)(batch*1024 + qtA*64);
  size_t qbaseB = (size_t)(batch*1024 + qtB*64);
  const int QKS = 3*DMODEL;
  const float scale = 0.03125f;              // D^-0.5 = 1/32

  bf16x8 bQhA[2], bQlA[2], bQhB[2], bQlB[2];
  {
    int qrow = w*16 + fr;
    size_t rbA = (qbaseA+qrow)*QKS + col0 + g*8;
    size_t rbB = (qbaseB+qrow)*QKS + col0 + g*8;
    bQhA[0] = *(const bf16x8*)&qkvh[rbA];
    bQhA[1] = *(const bf16x8*)&qkvh[rbA+32];
    bQlA[0] = *(const bf16x8*)&qkvl[rbA];
    bQlA[1] = *(const bf16x8*)&qkvl[rbA+32];
    bQhB[0] = *(const bf16x8*)&qkvh[rbB];
    bQhB[1] = *(const bf16x8*)&qkvh[rbB+32];
    bQlB[0] = *(const bf16x8*)&qkvl[rbB];
    bQlB[1] = *(const bf16x8*)&qkvl[rbB+32];
  }

  auto stageKV = [&](int buf, int kt){
    size_t kbase = (size_t)(batch*1024 + kt*64);
    #pragma unroll
    for (int j=0;j<2;j++){
      int c = j*256 + t, row = c>>3, seg = c&7;
      int lb = (j*256 + w*64)*8;
      size_t gk = (kbase+row)*QKS + 1024 + col0 + ((seg^(row&7))*8);
      gl16(qkvh+gk, &Kh[buf][lb]);
      gl16(qkvl+gk, &Kl[buf][lb]);
      size_t gv = (size_t)(col0+row)*TOK_N + kbase + ((seg^(row&7))*8);
      gl16(vth+gv, &Vh[buf][lb]);
      gl16(vtl+gv, &Vl[buf][lb]);
    }
  };

  float mA = -INFINITY, lA = 0.f, mB = -INFINITY, lB = 0.f;
  f32x4 oA[4], oB[4];
  #pragma unroll
  for (int nt=0;nt<4;nt++){ oA[nt]=(f32x4){0.f,0.f,0.f,0.f}; oB[nt]=(f32x4){0.f,0.f,0.f,0.f}; }

  auto process = [&](int cur, bool diag, bf16x8* bQh, bf16x8* bQl,
                     float& m_, float& l_, f32x4* o_){
    int ntmax = diag ? (w+1) : 4;
    f32x4 s[4];
    #pragma unroll
    for (int nt=0;nt<4;nt++) s[nt]=(f32x4){0.f,0.f,0.f,0.f};
    __builtin_amdgcn_s_setprio(1);
    #pragma unroll
    for (int ks=0; ks<2; ks++){
      #pragma unroll
      for (int nt=0; nt<4; nt++){
        if (nt < ntmax){
          int kvr = nt*16 + fr;
          int sc_ = (ks*4 + g) ^ (kvr&7);
          bf16x8 aKh = *(const bf16x8*)&Kh[cur][kvr*64 + sc_*8];
          bf16x8 aKl = *(const bf16x8*)&Kl[cur][kvr*64 + sc_*8];
          s[nt] = MFMA16(aKh, bQh[ks], s[nt]);
          s[nt] = MFMA16(aKl, bQh[ks], s[nt]);
          s[nt] = MFMA16(aKh, bQl[ks], s[nt]);
        }
      }
    }
    __builtin_amdgcn_s_setprio(0);
    float sv[4][4];
    float mx = -INFINITY;
    int ql = w*16 + fr;
    #pragma unroll
    for (int nt=0;nt<4;nt++)
      #pragma unroll
      for (int j=0;j<4;j++){
        float xv = s[nt][j]*scale;
        if (nt >= ntmax || (diag && (nt*16 + g*4 + j) > ql)) xv = -INFINITY;
        sv[nt][j] = xv;
        mx = fmaxf(mx, xv);
      }
    mx = fmaxf(mx, __shfl_xor(mx,16));
    mx = fmaxf(mx, __shfl_xor(mx,32));
    float nm = fmaxf(m_, mx);
    float scf = __expf(m_ - nm);
    float ps = 0.f;
    #pragma unroll
    for (int nt=0;nt<4;nt++)
      #pragma unroll
      for (int j=0;j<4;j++){
        float p = __expf(sv[nt][j] - nm);
        sv[nt][j] = p;
        ps += p;
      }
    ps += __shfl_xor(ps,16);
    ps += __shfl_xor(ps,32);
    l_ = l_*scf + ps;
    m_ = nm;
    #pragma unroll
    for (int nt=0;nt<4;nt++) o_[nt] = o_[nt]*scf;
    #pragma unroll
    for (int nt=0;nt<4;nt++){
      bf16x4 hv, lv;
      #pragma unroll
      for (int j=0;j<4;j++){
        float pv = sv[nt][j];
        __bf16 hb = (__bf16)pv;
        hv[j] = hb; lv[j] = (__bf16)(pv-(float)hb);
      }
      int el = fr*64 + (((2*nt + (g>>1)) ^ (fr&7))*8) + (g&1)*4;
      *(bf16x4*)&Pt[0][w][el] = hv;
      *(bf16x4*)&Pt[1][w][el] = lv;
    }
    int ksmax = (diag && w < 2) ? 1 : 2;
    __builtin_amdgcn_s_setprio(1);
    #pragma unroll
    for (int ks=0; ks<2; ks++){
      if (ks < ksmax){
        int pc = (4*ks + g) ^ (fr&7);
        bf16x8 bPh = *(const bf16x8*)&Pt[0][w][fr*64 + pc*8];
        bf16x8 bPl = *(const bf16x8*)&Pt[1][w][fr*64 + pc*8];
        #pragma unroll
        for (int nt=0; nt<4; nt++){
          int vr = nt*16 + fr;
          int vc = (ks*4 + g) ^ (vr&7);
          bf16x8 aVh = *(const bf16x8*)&Vh[cur][vr*64 + vc*8];
          bf16x8 aVl = *(const bf16x8*)&Vl[cur][vr*64 + vc*8];
          o_[nt] = MFMA16(aVh, bPh, o_[nt]);
          o_[nt] = MFMA16(aVl, bPh, o_[nt]);
          o_[nt] = MFMA16(aVh, bPl, o_[nt]);
        }
      }
    }
    __builtin_amdgcn_s_setprio(0);
  };

  stageKV(0, 0);
  for (int kt=0; kt<=qtB; kt++){
    int cur = kt&1;
    __syncthreads();
    if (kt < qtB) stageKV(cur^1, kt+1);
    if (kt <= qtA) process(cur, kt==qtA, bQhA, bQlA, mA, lA, oA);
    process(cur, kt==qtB, bQhB, bQlB, mB, lB, oB);
  }

  auto writeOut = [&](size_t qbase, float l_, f32x4* o_){
    float inv = 1.0f/l_;
    #pragma unroll
    for (int nt=0;nt<4;nt++){
      bf16x4 hv, lv;
      #pragma unroll
      for (int j=0;j<4;j++){
        float val = o_[nt][j]*inv;
        __bf16 hb = (__bf16)val;
        hv[j] = hb; lv[j] = (__bf16)(val-(float)hb);
      }
      int el = fr*64 + (((2*nt + (g>>1)) ^ (fr&7))*8) + (g&1)*4;
      *(bf16x4*)&Pt[0][w][el] = hv;
      *(bf16x4*)&Pt[1][w][el] = lv;
    }
    #pragma unroll
    for (int r=0;r<2;r++){
      int c = r*4 + g;
      int el = fr*64 + ((c ^ (fr&7))*8);
      bf16x8 vh = *(const bf16x8*)&Pt[0][w][el];
      bf16x8 vl = *(const bf16x8*)&Pt[1][w][el];
      size_t go = (qbase + w*16 + fr)*DMODEL + col0 + c*8;
      *(bf16x8*)&oh[go] = vh;
      *(bf16x8*)&ol[go] = vl;
    }
  };
  writeOut(qbaseA, lA, oA);
  writeOut(qbaseB, lB, oB);
}

// ---------------- capacity scan + slot assignment (+ tsrc inverse + zero pad) ----------------
__global__ __launch_bounds__(256) void scan_kernel(const int* __restrict__ idx2,
    const float* __restrict__ gate2, const int* __restrict__ nskv,
    int* __restrict__ tok, float* __restrict__ gsel, float* __restrict__ zbuf,
    int* __restrict__ tsrc)
{
  int t = threadIdx.x;
  for (int i=t; i<NEXP*CAPMAX; i+=256){ tok[i]=TOK_N; gsel[i]=0.f; }
  for (int i=t; i<2*TOK_N; i+=256) tsrc[i] = -1;
  for (int i=t; i<1024; i+=256) zbuf[i]=0.f;
  __shared__ int cnts[256][NEXP];
  __shared__ int nns_part[256];
  __shared__ int cap_s;
  int loc[NEXP];
  #pragma unroll
  for (int e=0;e<NEXP;e++) loc[e]=0;
  int nn=0, base = t*16;
  for (int u=0;u<16;u++){
    int n = base+u;
    if (nskv[n]){ nn++; loc[idx2[n*2]]++; loc[idx2[n*2+1]]++; }
  }
  #pragma unroll
  for (int e=0;e<NEXP;e++) cnts[t][e]=loc[e];
  nns_part[t]=nn;
  __syncthreads();
  if (t < NEXP){ int run=0; for (int i=0;i<256;i++){ int c=cnts[i][t]; cnts[i][t]=run; run+=c; } }
  if (t == NEXP){ int sum=0; for (int i=0;i<256;i++) sum+=nns_part[i]; cap_s = sum/4; }
  __syncthreads();
  int capacity = cap_s;
  int run[NEXP];
  #pragma unroll
  for (int e=0;e<NEXP;e++) run[e]=cnts[t][e];
  for (int u=0;u<16;u++){
    int n = base+u;
    if (!nskv[n]) continue;
    #pragma unroll
    for (int kk=0;kk<2;kk++){
      int e = idx2[n*2+kk];
      int r = run[e]++;
      if (r < capacity){
        tok[e*CAPMAX+r]=n; gsel[e*CAPMAX+r]=gate2[n*2+kk];
        tsrc[n*2+kk] = e*CAPMAX + r;
      }
    }
  }
}

extern "C" void kernel_launch(void* const* d_in, const int* in_sizes, int n_in,
                              void* d_out, int out_size, void* d_ws, size_t ws_size,
                              hipStream_t stream) {
  const float* x      = (const float*)d_in[0];
  const float* noise  = (const float*)d_in[1];
  const float* ln1_g  = (const float*)d_in[2];
  const float* ln1_b  = (const float*)d_in[3];
  const float* wq     = (const float*)d_in[4];
  const float* wk     = (const float*)d_in[5];
  const float* wv     = (const float*)d_in[6];
  const float* w_proj = (const float*)d_in[7];
  const float* b_proj = (const float*)d_in[8];
  const float* ln2_g  = (const float*)d_in[9];
  const float* ln2_b  = (const float*)d_in[10];
  const float* w_rout = (const float*)d_in[11];
  const float* b_rout = (const float*)d_in[12];
  const float* w_noi  = (const float*)d_in[13];
  const float* b_noi  = (const float*)d_in[14];
  const float* w_skip = (const float*)d_in[15];
  const float* b_skip = (const float*)d_in[16];
  const float* ew1    = (const float*)d_in[17];
  const float* eb1    = (const float*)d_in[18];
  const float* ew2    = (const float*)d_in[19];
  const float* eb2    = (const float*)d_in[20];
  float* out = (float*)d_out;

  char* ws = (char*)d_ws;
  const size_t MB = 1024*1024;
  // ---- trunk phase (fixed) ----
  __bf16* h_hi   = (__bf16*)(ws + 0*MB);
  __bf16* h_lo   = (__bf16*)(ws + 8*MB);
  __bf16* qkv_hi = (__bf16*)(ws + 16*MB);
  __bf16* qkv_lo = (__bf16*)(ws + 40*MB);
  __bf16* wAllT_h= (__bf16*)(ws + 64*MB);
  __bf16* wAllT_l= (__bf16*)(ws + 72*MB);
  __bf16* vt_hi  = (__bf16*)(ws + 81*MB);
  __bf16* vt_lo  = (__bf16*)(ws + 89*MB);
  float*  pP     = (float*) (ws + 16*MB);    // proj partials (qkv dead)
  __bf16* ao_hi = h_hi, *ao_lo = h_lo;

  // ---- expert-phase tier by ws_size (deterministic; constant across calls) ----
  int G; size_t off_mid, off_yk, off_e1, off_e2, off_meta;
  if (ws_size >= (size_t)338*MB){
    G = 8;  off_mid = 16;  off_yk = 80;  off_e1 = 208; off_e2 = 272; off_meta = 336;
  } else if (ws_size >= (size_t)178*MB){
    G = 4;  off_mid = 16;  off_yk = 48;  off_e1 = 112; off_e2 = 144; off_meta = 176;
  } else {
    G = 2;  off_e1 = 16;  off_e2 = 32;  off_mid = 48;  off_yk = 64;  off_meta = 96;
  }
  __bf16* e1T = (__bf16*)(ws + off_e1*MB);   // [G][DFF][D]
  __bf16* e2T = (__bf16*)(ws + off_e2*MB);   // [G][D][DFF]
  __bf16* mid = (__bf16*)(ws + off_mid*MB);  // [G][CAP][DFF]
  float*  yk  = (float*) (ws + off_yk*MB);   // [4G][CAP][D]
  char* meta = ws + off_meta*MB;
  int*   idx2  = (int*)  (meta);
  float* gate2 = (float*)(meta + 32*1024);
  int*   nskv  = (int*)  (meta + 64*1024);
  int*   tokb  = (int*)  (meta + 80*1024);
  float* gselb = (float*)(meta + 112*1024);
  float* zbuf  = (float*)(meta + 144*1024);
  int*   tsrc  = (int*)  (meta + 160*1024);

  dim3 blk(256);
  prep_kernel<<<5120, blk, 0, stream>>>(wq, wk, wv, w_proj, wAllT_h, wAllT_l,
                                        x, ln1_g, ln1_b, h_hi, h_lo);
  mgemm<0,true><<<dim3(24,32), blk, 0, stream>>>(h_hi, h_lo, DMODEL, wAllT_h, wAllT_l, DMODEL,
      nullptr, nullptr, qkv_hi, qkv_lo, 3*DMODEL, DMODEL, nullptr, nullptr);
  btrans_kernel<<<dim3(64,16), blk, 0, stream>>>(qkv_hi, qkv_lo, 3*DMODEL, 2048, vt_hi, vt_lo);
  attn_mfma_kernel<<<dim3(8,64), blk, 0, stream>>>(qkv_hi, qkv_lo, vt_hi, vt_lo, ao_hi, ao_lo);
  mgemm<5,true><<<dim3(8,32,2), blk, 0, stream>>>(ao_hi, ao_lo, DMODEL,
      wAllT_h + (size_t)3*DMODEL*DMODEL, wAllT_l + (size_t)3*DMODEL*DMODEL, DMODEL,
      nullptr, pP, nullptr, nullptr, DMODEL, 512, nullptr, nullptr);
  ln_router_kernel<<<TOK_N, blk, 0, stream>>>(pP, pP + (size_t)TOK_N*DMODEL, x, b_proj,
      ln2_g, ln2_b, h_hi, h_lo, out,
      w_rout, b_rout, w_noi, b_noi, w_skip, b_skip, noise, idx2, gate2, nskv);
  scan_kernel<<<1, blk, 0, stream>>>(idx2, gate2, nskv, tokb, gselb, zbuf, tsrc);
  // experts in groups of G: tconv -> up -> down(split-K 4) -> per-token gather
  int ngrp = NEXP / G;
  for (int grp=0; grp<ngrp; grp++){
    int e0 = grp*G;
    tconv_group<<<dim3(64,16,2*G), blk, 0, stream>>>(ew1, ew2, e1T, e2T, e0, G);
    mgemm<2,false><<<dim3(32,8,G), blk, 0, stream>>>(h_hi, nullptr, DMODEL,
        e1T, nullptr, DMODEL, eb1 + (size_t)e0*DFFD,
        nullptr, mid, nullptr, DFFD, DMODEL, tokb + e0*CAPMAX, (const __bf16*)zbuf);
    mgemm<4,false><<<dim3(8,8,4*G), blk, 0, stream>>>(mid, nullptr, DFFD,
        e2T, nullptr, DFFD, nullptr,
        yk, nullptr, nullptr, DMODEL, 1024, tokb + e0*CAPMAX, nullptr);
    gather_kernel<<<TOK_N, blk, 0, stream>>>(yk, tsrc, gselb, eb2, e0, G, out);
  }
}

// Round 18
// 503.489 us; speedup vs baseline: 1.1495x; 1.1495x over previous
//
#include <hip/hip_runtime.h>
#include <math.h>

#define TOK_N   4096
#define DMODEL  1024
#define NEXP    8
#define DFFD    4096
#define CAPMAX  1024

typedef __bf16 bf16x8 __attribute__((ext_vector_type(8)));
typedef __bf16 bf16x4 __attribute__((ext_vector_type(4)));
typedef float  f32x4  __attribute__((ext_vector_type(4)));

__device__ __forceinline__ f32x4 MFMA16(bf16x8 a, bf16x8 b, f32x4 c){
  return __builtin_amdgcn_mfma_f32_16x16x32_bf16(a, b, c, 0, 0, 0);
}

__device__ __forceinline__ void gl16(const __bf16* g, __bf16* l){
  __builtin_amdgcn_global_load_lds(
      (const __attribute__((address_space(1))) unsigned int*)g,
      (__attribute__((address_space(3))) unsigned int*)l, 16, 0, 0);
}

__device__ __forceinline__ float wave_sum(float x){
  #pragma unroll
  for (int o=32;o;o>>=1) x += __shfl_down(x,o);
  return x;
}

// -------- prep: tconv4 (wq/wk/wv/wproj -> wAllT split) + LN1 in one dispatch --------
__global__ __launch_bounds__(256) void prep_kernel(
    const float* __restrict__ wq, const float* __restrict__ wk,
    const float* __restrict__ wv, const float* __restrict__ wp,
    __bf16* __restrict__ dh, __bf16* __restrict__ dl,
    const float* __restrict__ x, const float* __restrict__ g1,
    const float* __restrict__ b1, __bf16* __restrict__ hh, __bf16* __restrict__ hl)
{
  __shared__ float smem[64*65];
  int b = blockIdx.x, t = threadIdx.x;
  if (b < 1024){
    int z = b >> 8, rem = b & 255;
    int k0 = (rem >> 4) * 64, n0 = (rem & 15) * 64;
    const float* in = z==0?wq: z==1?wk: z==2?wv: wp;
    __bf16* oh = dh + (size_t)z*DMODEL*DMODEL;
    __bf16* ol = dl + (size_t)z*DMODEL*DMODEL;
    float (*tile)[65] = (float(*)[65])smem;
    #pragma unroll
    for (int i=0;i<4;i++){
      int row = (t>>4) + i*16, col = (t&15)*4;
      f32x4 f = __builtin_nontemporal_load((const f32x4*)&in[(size_t)(k0+row)*DMODEL + n0 + col]);
      tile[row][col]=f[0]; tile[row][col+1]=f[1]; tile[row][col+2]=f[2]; tile[row][col+3]=f[3];
    }
    __syncthreads();
    #pragma unroll
    for (int i=0;i<2;i++){
      int c = t + i*256;
      int orow = c>>3, kg = (c&7)*8;
      bf16x8 hv, lv;
      #pragma unroll
      for (int u=0;u<8;u++){
        float xv = tile[kg+u][orow];
        __bf16 hb = (__bf16)xv;
        hv[u]=hb; lv[u]=(__bf16)(xv-(float)hb);
      }
      *(bf16x8*)&oh[(size_t)(n0+orow)*DMODEL + k0 + kg] = hv;
      *(bf16x8*)&ol[(size_t)(n0+orow)*DMODEL + k0 + kg] = lv;
    }
  } else {
    int n = b - 1024;
    float4 v = ((const float4*)(x + (size_t)n*DMODEL))[t];
    float s  = v.x+v.y+v.z+v.w;
    float sq = v.x*v.x+v.y*v.y+v.z*v.z+v.w*v.w;
    s = wave_sum(s); sq = wave_sum(sq);
    int lane = t & 63, wid = t >> 6;
    if (lane==0){ smem[wid]=s; smem[8+wid]=sq; }
    __syncthreads();
    if (t==0){
      float a = smem[0]+smem[1]+smem[2]+smem[3];
      float c = smem[8]+smem[9]+smem[10]+smem[11];
      float mean = a*(1.0f/DMODEL);
      float var  = c*(1.0f/DMODEL) - mean*mean;
      smem[16] = mean; smem[17] = 1.0f/sqrtf(var + 1e-5f);
    }
    __syncthreads();
    float mean = smem[16], rstd = smem[17];
    float4 g4 = ((const float4*)g1)[t];
    float4 b4 = ((const float4*)b1)[t];
    float o_[4];
    o_[0] = (v.x-mean)*rstd*g4.x + b4.x;
    o_[1] = (v.y-mean)*rstd*g4.y + b4.y;
    o_[2] = (v.z-mean)*rstd*g4.z + b4.z;
    o_[3] = (v.w-mean)*rstd*g4.w + b4.w;
    bf16x4 h4, l4;
    #pragma unroll
    for (int i=0;i<4;i++){ __bf16 hb=(__bf16)o_[i]; h4[i]=hb; l4[i]=(__bf16)(o_[i]-(float)hb); }
    *(bf16x4*)&hh[(size_t)n*DMODEL + t*4] = h4;
    *(bf16x4*)&hl[(size_t)n*DMODEL + t*4] = l4;
  }
}

// -------- proj-epilogue + LN2 + router + out-init fused --------
__global__ __launch_bounds__(256) void ln_router_kernel(
    const float* __restrict__ p0, const float* __restrict__ p1,
    const float* __restrict__ xres, const float* __restrict__ bproj,
    const float* __restrict__ g, const float* __restrict__ b,
    __bf16* __restrict__ oh, __bf16* __restrict__ ol, float* __restrict__ out,
    const float* __restrict__ wr, const float* __restrict__ br,
    const float* __restrict__ wn, const float* __restrict__ bn,
    const float* __restrict__ wsk, const float* __restrict__ bsk,
    const float* __restrict__ noise,
    int* __restrict__ idx2, float* __restrict__ gate2, int* __restrict__ nskv)
{
  int n = blockIdx.x, t = threadIdx.x;
  size_t ro = (size_t)n*DMODEL/4 + t;
  float4 a  = ((const float4*)p0)[ro];
  float4 a1 = ((const float4*)p1)[ro];
  float4 xr = ((const float4*)xres)[ro];
  float4 bp = ((const float4*)bproj)[t];
  float4 v;
  v.x = a.x+a1.x+xr.x+bp.x; v.y = a.y+a1.y+xr.y+bp.y;
  v.z = a.z+a1.z+xr.z+bp.z; v.w = a.w+a1.w+xr.w+bp.w;
  float s  = v.x+v.y+v.z+v.w;
  float sq = v.x*v.x+v.y*v.y+v.z*v.z+v.w*v.w;
  s = wave_sum(s); sq = wave_sum(sq);
  __shared__ float r1[4], r2[4];
  __shared__ float mean_s, rstd_s, sk_s;
  int lane = t & 63, wid = t >> 6;
  if (lane==0){ r1[wid]=s; r2[wid]=sq; }
  __syncthreads();
  if (t==0){
    float aa = r1[0]+r1[1]+r1[2]+r1[3];
    float cc = r2[0]+r2[1]+r2[2]+r2[3];
    float mean = aa*(1.0f/DMODEL);
    float var  = cc*(1.0f/DMODEL) - mean*mean;
    mean_s = mean; rstd_s = 1.0f/sqrtf(var + 1e-5f);
  }
  __syncthreads();
  float mean = mean_s, rstd = rstd_s;
  float4 g4 = ((const float4*)g)[t];
  float4 b4 = ((const float4*)b)[t];
  float o_[4];
  o_[0] = (v.x-mean)*rstd*g4.x + b4.x;
  o_[1] = (v.y-mean)*rstd*g4.y + b4.y;
  o_[2] = (v.z-mean)*rstd*g4.z + b4.z;
  o_[3] = (v.w-mean)*rstd*g4.w + b4.w;
  bf16x4 h4, l4;
  #pragma unroll
  for (int i=0;i<4;i++){ __bf16 hb=(__bf16)o_[i]; h4[i]=hb; l4[i]=(__bf16)(o_[i]-(float)hb); }
  *(bf16x4*)&oh[(size_t)n*DMODEL + t*4] = h4;
  *(bf16x4*)&ol[(size_t)n*DMODEL + t*4] = l4;
  // router on exact f32 h2
  int d0 = t*4;
  const float* wrp = wr + (size_t)d0*NEXP;
  const float* wnp = wn + (size_t)d0*NEXP;
  const float* wsp = wsk + d0;
  float vals[17];
  #pragma unroll
  for (int i=0;i<17;i++) vals[i]=0.f;
  #pragma unroll
  for (int i=0;i<4;i++){
    #pragma unroll
    for (int e=0;e<NEXP;e++){
      vals[e]   += o_[i]*wrp[i*NEXP+e];
      vals[8+e] += o_[i]*wnp[i*NEXP+e];
    }
    vals[16] += o_[i]*wsp[i];
  }
  __shared__ float red[4][17];
  #pragma unroll
  for (int i=0;i<17;i++){
    float xx = wave_sum(vals[i]);
    if (lane==0) red[wid][i] = xx;
  }
  __syncthreads();
  if (t==0){
    float noisy[NEXP];
    #pragma unroll
    for (int e=0;e<NEXP;e++){
      float lr = red[0][e]+red[1][e]+red[2][e]+red[3][e] + br[e];
      float pn = red[0][8+e]+red[1][8+e]+red[2][8+e]+red[3][8+e] + bn[e];
      float sp = fmaxf(pn,0.f) + log1pf(expf(-fabsf(pn)));
      noisy[e] = lr + noise[(size_t)n*NEXP + e]*sp;
    }
    float sk = red[0][16]+red[1][16]+red[2][16]+red[3][16] + bsk[0];
    sk_s = sk;
    nskv[n] = (sk <= 0.f) ? 1 : 0;
    int i0=0; float v0=noisy[0];
    #pragma unroll
    for (int e=1;e<NEXP;e++) if (noisy[e] > v0){ v0=noisy[e]; i0=e; }
    int i1=-1; float v1=-INFINITY;
    #pragma unroll
    for (int e=0;e<NEXP;e++) if (e!=i0 && noisy[e] > v1){ v1=noisy[e]; i1=e; }
    float tt = expf(v1 - v0);
    idx2[n*2+0]=i0; idx2[n*2+1]=i1;
    gate2[n*2+0]=1.0f/(1.0f+tt); gate2[n*2+1]=tt/(1.0f+tt);
  }
  __syncthreads();
  if (sk_s > 0.f){
    v.x += o_[0]; v.y += o_[1]; v.z += o_[2]; v.w += o_[3];
  }
  ((float4*)out)[ro] = v;
}

// -------- group expert weight transpose-convert (NT both sides) --------
__global__ __launch_bounds__(256) void tconv_group(
    const float* __restrict__ ew1, const float* __restrict__ ew2,
    __bf16* __restrict__ e1T, __bf16* __restrict__ e2T, int e0, int G)
{
  __shared__ float tile[64][65];
  int z = blockIdx.z, t = threadIdx.x;
  const float* in; __bf16* out; int K, N, k0, n0;
  if (z < G){
    in = ew1 + (size_t)(e0+z)*DMODEL*DFFD; out = e1T + (size_t)z*DFFD*DMODEL;
    K = DMODEL; N = DFFD; k0 = blockIdx.y*64; n0 = blockIdx.x*64;
  } else {
    in = ew2 + (size_t)(e0+z-G)*DFFD*DMODEL; out = e2T + (size_t)(z-G)*DMODEL*DFFD;
    K = DFFD; N = DMODEL; k0 = blockIdx.x*64; n0 = blockIdx.y*64;
  }
  #pragma unroll
  for (int i=0;i<4;i++){
    int row = (t>>4) + i*16, col = (t&15)*4;
    f32x4 f = __builtin_nontemporal_load((const f32x4*)&in[(size_t)(k0+row)*N + n0 + col]);
    tile[row][col]=f[0]; tile[row][col+1]=f[1]; tile[row][col+2]=f[2]; tile[row][col+3]=f[3];
  }
  __syncthreads();
  #pragma unroll
  for (int i=0;i<2;i++){
    int c = t + i*256;
    int orow = c>>3, kg = (c&7)*8;
    bf16x8 hv;
    #pragma unroll
    for (int u=0;u<8;u++) hv[u] = (__bf16)tile[kg+u][orow];
    __builtin_nontemporal_store(hv, (bf16x8*)&out[(size_t)(n0+orow)*K + k0 + kg]);
  }
}

// ------- bf16-pair transpose: qkv v-slice -> vT[1024][4096] -------
__global__ __launch_bounds__(256) void btrans_kernel(
    const __bf16* __restrict__ ih, const __bf16* __restrict__ il, int istride, int icol0,
    __bf16* __restrict__ oh, __bf16* __restrict__ ol){
  __shared__ __bf16 th[64][72], tl[64][72];
  int r0 = blockIdx.x*64, c0 = blockIdx.y*64;
  int t = threadIdx.x;
  {
    int r = t>>2, cg = (t&3)*16;
    size_t go = (size_t)(r0+r)*istride + icol0 + c0 + cg;
    *(bf16x8*)&th[r][cg]   = *(const bf16x8*)&ih[go];
    *(bf16x8*)&th[r][cg+8] = *(const bf16x8*)&ih[go+8];
    *(bf16x8*)&tl[r][cg]   = *(const bf16x8*)&il[go];
    *(bf16x8*)&tl[r][cg+8] = *(const bf16x8*)&il[go+8];
  }
  __syncthreads();
  {
    int c = t>>2, rg = (t&3)*16;
    bf16x8 a,b,e,f;
    #pragma unroll
    for (int u=0;u<8;u++){ a[u]=th[rg+u][c]; b[u]=th[rg+8+u][c]; e[u]=tl[rg+u][c]; f[u]=tl[rg+8+u][c]; }
    size_t go = (size_t)(c0+c)*TOK_N + r0 + rg;
    *(bf16x8*)&oh[go]   = a;
    *(bf16x8*)&oh[go+8] = b;
    *(bf16x8*)&ol[go]   = e;
    *(bf16x8*)&ol[go+8] = f;
  }
}

// ---------------- MFMA GEMM, 128x128, BK=32, counted-vmcnt pipeline (T3/T4) ----------------
// MODE 0: QKV  -> Ch/Cl hi/lo bf16 (N=3072)
// MODE 2: UP   -> Ch = bf16(relu(acc+bias)); A gathered via tok; z = expert-in-group
// MODE 4: DOWN -> Cf partial; z = (group-expert<<2)|kchunk, K=1024
// MODE 5: PROJK-> Cf partial; z = K-chunk of 512
template<int MODE, bool SPLIT>
__global__ __launch_bounds__(256) void mgemm(
    const __bf16* __restrict__ Ah, const __bf16* __restrict__ Al, int Astride,
    const __bf16* __restrict__ Bh, const __bf16* __restrict__ Bl, int Bstride,
    const float* __restrict__ bias,
    float* __restrict__ Cf, __bf16* __restrict__ Ch, __bf16* __restrict__ Cl,
    int N, int K,
    const int* __restrict__ tok, const __bf16* __restrict__ zbuf)
{
  if constexpr (MODE==2){
    int z = blockIdx.z;
    Bh  += (size_t)z*((size_t)DFFD*DMODEL);
    bias+= (size_t)z*DFFD;
    Ch  += (size_t)z*((size_t)CAPMAX*DFFD);
    tok += z*CAPMAX;
  }
  if constexpr (MODE==4){
    int ge = blockIdx.z>>2, kz = blockIdx.z&3;
    Ah  += (size_t)ge*((size_t)CAPMAX*DFFD) + kz*1024;
    Bh  += (size_t)ge*((size_t)DMODEL*DFFD) + kz*1024;
    Cf  += (size_t)blockIdx.z*((size_t)CAPMAX*DMODEL);
    tok += ge*CAPMAX;
  }
  if constexpr (MODE==5){
    int kz = blockIdx.z;
    Ah += kz*512; Al += kz*512; Bh += kz*512; Bl += kz*512;
    Cf += (size_t)kz*((size_t)TOK_N*DMODEL);
  }
  int m0 = blockIdx.y*128, n0 = blockIdx.x*128;
  if ((MODE==2||MODE==4) && tok[m0] >= TOK_N) return;   // valid slots are a prefix (before any barrier)
  __shared__ __align__(16) __bf16 sAh[2*128*32], sBh[2*128*32];
  __shared__ __align__(16) __bf16 sAl[SPLIT?2*128*32:8], sBl[SPLIT?2*128*32:8];
  int t = threadIdx.x, lane = t&63, w = t>>6;
  int wr = w>>1, wc = w&1, fr = lane&15, kb = lane>>4;

  const __bf16* aB[2]; const __bf16* aBl[2]; bool aval[2];
  const __bf16* bB[2]; const __bf16* bBl[2];
  #pragma unroll
  for (int j=0;j<2;j++){
    int c = j*256 + w*64 + lane;
    int row = c>>2, grp = c&3;
    int sg = grp ^ ((row>>1)&3);           // pre-swizzled source chunk (involution)
    if (MODE==2){
      int token = tok[m0+row];
      if (token < TOK_N){ aB[j] = Ah + (size_t)token*Astride + sg*8; aval[j]=true; }
      else              { aB[j] = zbuf + sg*8;                       aval[j]=false; }
    } else {
      aB[j] = Ah + (size_t)(m0+row)*Astride + sg*8; aval[j]=true;
      if (SPLIT) aBl[j] = Al + (size_t)(m0+row)*Astride + sg*8;
    }
    bB[j] = Bh + (size_t)(n0+row)*Bstride + sg*8;
    if (SPLIT) bBl[j] = Bl + (size_t)(n0+row)*Bstride + sg*8;
  }

  auto stage = [&](int buf, int kt){       // SPLIT: 8 vmem ops/wave; else 4
    int base = buf*(128*32);
    #pragma unroll
    for (int j=0;j<2;j++){
      int cb8 = base + (j*256 + w*64)*8;
      gl16(aB[j] + (aval[j]? kt : 0), &sAh[cb8]);
      gl16(bB[j] + kt, &sBh[cb8]);
      if constexpr (SPLIT){
        gl16(aBl[j] + kt, &sAl[cb8]);
        gl16(bBl[j] + kt, &sBl[cb8]);
      }
    }
  };

  f32x4 acc[4][4];
  #pragma unroll
  for (int mt=0;mt<4;mt++)
    #pragma unroll
    for (int nt=0;nt<4;nt++) acc[mt][nt] = (f32x4){0.f,0.f,0.f,0.f};

  int nk = K >> 5;
  stage(0, 0);
  stage(1, 32);                            // all shapes have nk >= 2
  int xk = (kb ^ ((fr>>1)&3))*8;           // swizzled read slot within row
  for (int ik=0; ik<nk; ik++){
    int cur = ik & 1;
    if (ik+1 < nk){
      if constexpr (SPLIT) asm volatile("s_waitcnt vmcnt(8)" ::: "memory");
      else                 asm volatile("s_waitcnt vmcnt(4)" ::: "memory");
    } else {
      asm volatile("s_waitcnt vmcnt(0)" ::: "memory");
    }
    __builtin_amdgcn_s_barrier();          // every wave has its cur-buffer complete
    int fb = cur*(128*32);
    bf16x8 aFh[4], bFh[4];
    bf16x8 aFl[SPLIT?4:1], bFl[SPLIT?4:1];
    #pragma unroll
    for (int mt=0;mt<4;mt++) aFh[mt] = *(const bf16x8*)&sAh[fb + (wr*64+mt*16+fr)*32 + xk];
    #pragma unroll
    for (int nt=0;nt<4;nt++) bFh[nt] = *(const bf16x8*)&sBh[fb + (wc*64+nt*16+fr)*32 + xk];
    if constexpr (SPLIT){
      #pragma unroll
      for (int mt=0;mt<4;mt++) aFl[mt] = *(const bf16x8*)&sAl[fb + (wr*64+mt*16+fr)*32 + xk];
      #pragma unroll
      for (int nt=0;nt<4;nt++) bFl[nt] = *(const bf16x8*)&sBl[fb + (wc*64+nt*16+fr)*32 + xk];
    }
    asm volatile("s_waitcnt lgkmcnt(0)" ::: "memory");   // frags landed in regs
    __builtin_amdgcn_sched_barrier(0);                    // rule #18 fence
    __builtin_amdgcn_s_barrier();          // no wave still reading buf[cur]
    if (ik+2 < nk) stage(cur, (ik+2)<<5);  // refill cur; flies under MFMA + next step
    __builtin_amdgcn_s_setprio(1);
    #pragma unroll
    for (int mt=0;mt<4;mt++)
      #pragma unroll
      for (int nt=0;nt<4;nt++)
        acc[mt][nt] = MFMA16(aFh[mt], bFh[nt], acc[mt][nt]);
    if constexpr (SPLIT){
      #pragma unroll
      for (int mt=0;mt<4;mt++)
        #pragma unroll
        for (int nt=0;nt<4;nt++){
          acc[mt][nt] = MFMA16(aFh[mt], bFl[nt], acc[mt][nt]);
          acc[mt][nt] = MFMA16(aFl[mt], bFh[nt], acc[mt][nt]);
        }
    }
    __builtin_amdgcn_s_setprio(0);
  }

  #pragma unroll
  for (int mt=0; mt<4; mt++){
    int r0 = m0 + wr*64 + mt*16 + (lane>>4)*4;
    #pragma unroll
    for (int nt=0; nt<4; nt++){
      int col = n0 + wc*64 + nt*16 + fr;
      f32x4 v = acc[mt][nt];
      if constexpr (MODE==0){
        #pragma unroll
        for (int jj=0;jj<4;jj++){
          float val = v[jj];
          __bf16 hb = (__bf16)val;
          size_t idx = (size_t)(r0+jj)*N + col;
          Ch[idx] = hb; Cl[idx] = (__bf16)(val-(float)hb);
        }
      } else if constexpr (MODE==2){
        float bs = bias[col];
        #pragma unroll
        for (int jj=0;jj<4;jj++)
          Ch[(size_t)(r0+jj)*N + col] = (__bf16)fmaxf(v[jj]+bs, 0.f);
      } else {  // MODE 4 / 5: raw partial (cached — consumer reads it next)
        #pragma unroll
        for (int jj=0;jj<4;jj++)
          Cf[(size_t)(r0+jj)*N + col] = v[jj];
      }
    }
  }
}

// ------- per-token gather (race-free): out[n] += sum over this group's picks -------
__global__ __launch_bounds__(256) void gather_kernel(const float* __restrict__ yk,
    const int* __restrict__ tsrc, const float* __restrict__ gselb,
    const float* __restrict__ eb2, int e0, int G, float* __restrict__ out)
{
  int n = blockIdx.x, t = threadIdx.x;
  int s0 = tsrc[n*2], s1 = tsrc[n*2+1];
  float4 o; bool any = false;
  #pragma unroll
  for (int kk=0; kk<2; kk++){
    int src = kk ? s1 : s0;
    if (src < 0) continue;
    int e = src >> 10;
    int ge = e - e0;
    if (ge < 0 || ge >= G) continue;
    int r = src & (CAPMAX-1);
    if (!any){ o = ((const float4*)(out + (size_t)n*DMODEL))[t]; any = true; }
    float g = gselb[src];
    float4 acc = ((const float4*)(eb2 + (size_t)e*DMODEL))[t];
    #pragma unroll
    for (int z=0; z<4; z++){
      float4 p = ((const float4*)(yk + ((size_t)(ge*4+z)*CAPMAX + r)*DMODEL))[t];
      acc.x+=p.x; acc.y+=p.y; acc.z+=p.z; acc.w+=p.w;
    }
    o.x += g*acc.x; o.y += g*acc.y; o.z += g*acc.z; o.w += g*acc.w;
  }
  if (any) ((float4*)(out + (size_t)n*DMODEL))[t] = o;
}

// ---------------- MFMA causal flash attention, split-bf16, swapped operands ----------------
// Each block owns TWO q-tiles (qtA=blk, qtB=blk+8) of one (b,h): K/V staging shared.
__global__ __launch_bounds__(256) void attn_mfma_kernel(
    const __bf16* __restrict__ qkvh, const __bf16* __restrict__ qkvl,
    const __bf16* __restrict__ vth, const __bf16* __restrict__ vtl,
    __bf16* __restrict__ oh, __bf16* __restrict__ ol)
{
  __shared__ __align__(16) __bf16 Kh[2][64*64], Kl[2][64*64], Vh[2][64*64], Vl[2][64*64];
  __shared__ __align__(16) __bf16 Pt[2][4][16*64];
  int qtA = blockIdx.x, qtB = qtA + 8;
  int bh = blockIdx.y;
  int batch = bh>>4, head = bh&15;
  int t = threadIdx.x, lane = t&63, w = t>>6;
  int g = lane>>4, fr = lane&15;
  int col0 = head*64;
  size_t qbaseA = (size_t)(batch*1024 + qtA*64);
  size_t qbaseB = (size_t)(batch*1024 + qtB*64);
  const int QKS = 3*DMODEL;
  const float scale = 0.03125f;              // D^-0.5 = 1/32

  bf16x8 bQhA[2], bQlA[2], bQhB[2], bQlB[2];
  {
    int qrow = w*16 + fr;
    size_t rbA = (qbaseA+qrow)*QKS + col0 + g*8;
    size_t rbB = (qbaseB+qrow)*QKS + col0 + g*8;
    bQhA[0] = *(const bf16x8*)&qkvh[rbA];
    bQhA[1] = *(const bf16x8*)&qkvh[rbA+32];
    bQlA[0] = *(const bf16x8*)&qkvl[rbA];
    bQlA[1] = *(const bf16x8*)&qkvl[rbA+32];
    bQhB[0] = *(const bf16x8*)&qkvh[rbB];
    bQhB[1] = *(const bf16x8*)&qkvh[rbB+32];
    bQlB[0] = *(const bf16x8*)&qkvl[rbB];
    bQlB[1] = *(const bf16x8*)&qkvl[rbB+32];
  }

  auto stageKV = [&](int buf, int kt){
    size_t kbase = (size_t)(batch*1024 + kt*64);
    #pragma unroll
    for (int j=0;j<2;j++){
      int c = j*256 + t, row = c>>3, seg = c&7;
      int lb = (j*256 + w*64)*8;
      size_t gk = (kbase+row)*QKS + 1024 + col0 + ((seg^(row&7))*8);
      gl16(qkvh+gk, &Kh[buf][lb]);
      gl16(qkvl+gk, &Kl[buf][lb]);
      size_t gv = (size_t)(col0+row)*TOK_N + kbase + ((seg^(row&7))*8);
      gl16(vth+gv, &Vh[buf][lb]);
      gl16(vtl+gv, &Vl[buf][lb]);
    }
  };

  float mA = -INFINITY, lA = 0.f, mB = -INFINITY, lB = 0.f;
  f32x4 oA[4], oB[4];
  #pragma unroll
  for (int nt=0;nt<4;nt++){ oA[nt]=(f32x4){0.f,0.f,0.f,0.f}; oB[nt]=(f32x4){0.f,0.f,0.f,0.f}; }

  auto process = [&](int cur, bool diag, bf16x8* bQh, bf16x8* bQl,
                     float& m_, float& l_, f32x4* o_){
    int ntmax = diag ? (w+1) : 4;
    f32x4 s[4];
    #pragma unroll
    for (int nt=0;nt<4;nt++) s[nt]=(f32x4){0.f,0.f,0.f,0.f};
    __builtin_amdgcn_s_setprio(1);
    #pragma unroll
    for (int ks=0; ks<2; ks++){
      #pragma unroll
      for (int nt=0; nt<4; nt++){
        if (nt < ntmax){
          int kvr = nt*16 + fr;
          int sc_ = (ks*4 + g) ^ (kvr&7);
          bf16x8 aKh = *(const bf16x8*)&Kh[cur][kvr*64 + sc_*8];
          bf16x8 aKl = *(const bf16x8*)&Kl[cur][kvr*64 + sc_*8];
          s[nt] = MFMA16(aKh, bQh[ks], s[nt]);
          s[nt] = MFMA16(aKl, bQh[ks], s[nt]);
          s[nt] = MFMA16(aKh, bQl[ks], s[nt]);
        }
      }
    }
    __builtin_amdgcn_s_setprio(0);
    float sv[4][4];
    float mx = -INFINITY;
    int ql = w*16 + fr;
    #pragma unroll
    for (int nt=0;nt<4;nt++)
      #pragma unroll
      for (int j=0;j<4;j++){
        float xv = s[nt][j]*scale;
        if (nt >= ntmax || (diag && (nt*16 + g*4 + j) > ql)) xv = -INFINITY;
        sv[nt][j] = xv;
        mx = fmaxf(mx, xv);
      }
    mx = fmaxf(mx, __shfl_xor(mx,16));
    mx = fmaxf(mx, __shfl_xor(mx,32));
    float nm = fmaxf(m_, mx);
    float scf = __expf(m_ - nm);
    float ps = 0.f;
    #pragma unroll
    for (int nt=0;nt<4;nt++)
      #pragma unroll
      for (int j=0;j<4;j++){
        float p = __expf(sv[nt][j] - nm);
        sv[nt][j] = p;
        ps += p;
      }
    ps += __shfl_xor(ps,16);
    ps += __shfl_xor(ps,32);
    l_ = l_*scf + ps;
    m_ = nm;
    #pragma unroll
    for (int nt=0;nt<4;nt++) o_[nt] = o_[nt]*scf;
    #pragma unroll
    for (int nt=0;nt<4;nt++){
      bf16x4 hv, lv;
      #pragma unroll
      for (int j=0;j<4;j++){
        float pv = sv[nt][j];
        __bf16 hb = (__bf16)pv;
        hv[j] = hb; lv[j] = (__bf16)(pv-(float)hb);
      }
      int el = fr*64 + (((2*nt + (g>>1)) ^ (fr&7))*8) + (g&1)*4;
      *(bf16x4*)&Pt[0][w][el] = hv;
      *(bf16x4*)&Pt[1][w][el] = lv;
    }
    int ksmax = (diag && w < 2) ? 1 : 2;
    __builtin_amdgcn_s_setprio(1);
    #pragma unroll
    for (int ks=0; ks<2; ks++){
      if (ks < ksmax){
        int pc = (4*ks + g) ^ (fr&7);
        bf16x8 bPh = *(const bf16x8*)&Pt[0][w][fr*64 + pc*8];
        bf16x8 bPl = *(const bf16x8*)&Pt[1][w][fr*64 + pc*8];
        #pragma unroll
        for (int nt=0; nt<4; nt++){
          int vr = nt*16 + fr;
          int vc = (ks*4 + g) ^ (vr&7);
          bf16x8 aVh = *(const bf16x8*)&Vh[cur][vr*64 + vc*8];
          bf16x8 aVl = *(const bf16x8*)&Vl[cur][vr*64 + vc*8];
          o_[nt] = MFMA16(aVh, bPh, o_[nt]);
          o_[nt] = MFMA16(aVl, bPh, o_[nt]);
          o_[nt] = MFMA16(aVh, bPl, o_[nt]);
        }
      }
    }
    __builtin_amdgcn_s_setprio(0);
  };

  stageKV(0, 0);
  for (int kt=0; kt<=qtB; kt++){
    int cur = kt&1;
    __syncthreads();
    if (kt < qtB) stageKV(cur^1, kt+1);
    if (kt <= qtA) process(cur, kt==qtA, bQhA, bQlA, mA, lA, oA);
    process(cur, kt==qtB, bQhB, bQlB, mB, lB, oB);
  }

  auto writeOut = [&](size_t qbase, float l_, f32x4* o_){
    float inv = 1.0f/l_;
    #pragma unroll
    for (int nt=0;nt<4;nt++){
      bf16x4 hv, lv;
      #pragma unroll
      for (int j=0;j<4;j++){
        float val = o_[nt][j]*inv;
        __bf16 hb = (__bf16)val;
        hv[j] = hb; lv[j] = (__bf16)(val-(float)hb);
      }
      int el = fr*64 + (((2*nt + (g>>1)) ^ (fr&7))*8) + (g&1)*4;
      *(bf16x4*)&Pt[0][w][el] = hv;
      *(bf16x4*)&Pt[1][w][el] = lv;
    }
    #pragma unroll
    for (int r=0;r<2;r++){
      int c = r*4 + g;
      int el = fr*64 + ((c ^ (fr&7))*8);
      bf16x8 vh = *(const bf16x8*)&Pt[0][w][el];
      bf16x8 vl = *(const bf16x8*)&Pt[1][w][el];
      size_t go = (qbase + w*16 + fr)*DMODEL + col0 + c*8;
      *(bf16x8*)&oh[go] = vh;
      *(bf16x8*)&ol[go] = vl;
    }
  };
  writeOut(qbaseA, lA, oA);
  writeOut(qbaseB, lB, oB);
}

// ---------------- capacity scan + slot assignment (+ tsrc inverse + zero pad) ----------------
__global__ __launch_bounds__(256) void scan_kernel(const int* __restrict__ idx2,
    const float* __restrict__ gate2, const int* __restrict__ nskv,
    int* __restrict__ tok, float* __restrict__ gsel, float* __restrict__ zbuf,
    int* __restrict__ tsrc)
{
  int t = threadIdx.x;
  for (int i=t; i<NEXP*CAPMAX; i+=256){ tok[i]=TOK_N; gsel[i]=0.f; }
  for (int i=t; i<2*TOK_N; i+=256) tsrc[i] = -1;
  for (int i=t; i<1024; i+=256) zbuf[i]=0.f;
  __shared__ int cnts[256][NEXP];
  __shared__ int nns_part[256];
  __shared__ int cap_s;
  int loc[NEXP];
  #pragma unroll
  for (int e=0;e<NEXP;e++) loc[e]=0;
  int nn=0, base = t*16;
  for (int u=0;u<16;u++){
    int n = base+u;
    if (nskv[n]){ nn++; loc[idx2[n*2]]++; loc[idx2[n*2+1]]++; }
  }
  #pragma unroll
  for (int e=0;e<NEXP;e++) cnts[t][e]=loc[e];
  nns_part[t]=nn;
  __syncthreads();
  if (t < NEXP){ int run=0; for (int i=0;i<256;i++){ int c=cnts[i][t]; cnts[i][t]=run; run+=c; } }
  if (t == NEXP){ int sum=0; for (int i=0;i<256;i++) sum+=nns_part[i]; cap_s = sum/4; }
  __syncthreads();
  int capacity = cap_s;
  int run[NEXP];
  #pragma unroll
  for (int e=0;e<NEXP;e++) run[e]=cnts[t][e];
  for (int u=0;u<16;u++){
    int n = base+u;
    if (!nskv[n]) continue;
    #pragma unroll
    for (int kk=0;kk<2;kk++){
      int e = idx2[n*2+kk];
      int r = run[e]++;
      if (r < capacity){
        tok[e*CAPMAX+r]=n; gsel[e*CAPMAX+r]=gate2[n*2+kk];
        tsrc[n*2+kk] = e*CAPMAX + r;
      }
    }
  }
}

extern "C" void kernel_launch(void* const* d_in, const int* in_sizes, int n_in,
                              void* d_out, int out_size, void* d_ws, size_t ws_size,
                              hipStream_t stream) {
  const float* x      = (const float*)d_in[0];
  const float* noise  = (const float*)d_in[1];
  const float* ln1_g  = (const float*)d_in[2];
  const float* ln1_b  = (const float*)d_in[3];
  const float* wq     = (const float*)d_in[4];
  const float* wk     = (const float*)d_in[5];
  const float* wv     = (const float*)d_in[6];
  const float* w_proj = (const float*)d_in[7];
  const float* b_proj = (const float*)d_in[8];
  const float* ln2_g  = (const float*)d_in[9];
  const float* ln2_b  = (const float*)d_in[10];
  const float* w_rout = (const float*)d_in[11];
  const float* b_rout = (const float*)d_in[12];
  const float* w_noi  = (const float*)d_in[13];
  const float* b_noi  = (const float*)d_in[14];
  const float* w_skip = (const float*)d_in[15];
  const float* b_skip = (const float*)d_in[16];
  const float* ew1    = (const float*)d_in[17];
  const float* eb1    = (const float*)d_in[18];
  const float* ew2    = (const float*)d_in[19];
  const float* eb2    = (const float*)d_in[20];
  float* out = (float*)d_out;

  char* ws = (char*)d_ws;
  const size_t MB = 1024*1024;
  // ---- trunk phase (fixed) ----
  __bf16* h_hi   = (__bf16*)(ws + 0*MB);
  __bf16* h_lo   = (__bf16*)(ws + 8*MB);
  __bf16* qkv_hi = (__bf16*)(ws + 16*MB);
  __bf16* qkv_lo = (__bf16*)(ws + 40*MB);
  __bf16* wAllT_h= (__bf16*)(ws + 64*MB);
  __bf16* wAllT_l= (__bf16*)(ws + 72*MB);
  __bf16* vt_hi  = (__bf16*)(ws + 81*MB);
  __bf16* vt_lo  = (__bf16*)(ws + 89*MB);
  float*  pP     = (float*) (ws + 16*MB);    // proj partials (qkv dead)
  __bf16* ao_hi = h_hi, *ao_lo = h_lo;

  // ---- expert-phase tier by ws_size (deterministic; constant across calls) ----
  int G; size_t off_mid, off_yk, off_e1, off_e2, off_meta;
  if (ws_size >= (size_t)338*MB){
    G = 8;  off_mid = 16;  off_yk = 80;  off_e1 = 208; off_e2 = 272; off_meta = 336;
  } else if (ws_size >= (size_t)178*MB){
    G = 4;  off_mid = 16;  off_yk = 48;  off_e1 = 112; off_e2 = 144; off_meta = 176;
  } else {
    G = 2;  off_e1 = 16;  off_e2 = 32;  off_mid = 48;  off_yk = 64;  off_meta = 96;
  }
  __bf16* e1T = (__bf16*)(ws + off_e1*MB);   // [G][DFF][D]
  __bf16* e2T = (__bf16*)(ws + off_e2*MB);   // [G][D][DFF]
  __bf16* mid = (__bf16*)(ws + off_mid*MB);  // [G][CAP][DFF]
  float*  yk  = (float*) (ws + off_yk*MB);   // [4G][CAP][D]
  char* meta = ws + off_meta*MB;
  int*   idx2  = (int*)  (meta);
  float* gate2 = (float*)(meta + 32*1024);
  int*   nskv  = (int*)  (meta + 64*1024);
  int*   tokb  = (int*)  (meta + 80*1024);
  float* gselb = (float*)(meta + 112*1024);
  float* zbuf  = (float*)(meta + 144*1024);
  int*   tsrc  = (int*)  (meta + 160*1024);

  dim3 blk(256);
  prep_kernel<<<5120, blk, 0, stream>>>(wq, wk, wv, w_proj, wAllT_h, wAllT_l,
                                        x, ln1_g, ln1_b, h_hi, h_lo);
  mgemm<0,true><<<dim3(24,32), blk, 0, stream>>>(h_hi, h_lo, DMODEL, wAllT_h, wAllT_l, DMODEL,
      nullptr, nullptr, qkv_hi, qkv_lo, 3*DMODEL, DMODEL, nullptr, nullptr);
  btrans_kernel<<<dim3(64,16), blk, 0, stream>>>(qkv_hi, qkv_lo, 3*DMODEL, 2048, vt_hi, vt_lo);
  attn_mfma_kernel<<<dim3(8,64), blk, 0, stream>>>(qkv_hi, qkv_lo, vt_hi, vt_lo, ao_hi, ao_lo);
  mgemm<5,true><<<dim3(8,32,2), blk, 0, stream>>>(ao_hi, ao_lo, DMODEL,
      wAllT_h + (size_t)3*DMODEL*DMODEL, wAllT_l + (size_t)3*DMODEL*DMODEL, DMODEL,
      nullptr, pP, nullptr, nullptr, DMODEL, 512, nullptr, nullptr);
  ln_router_kernel<<<TOK_N, blk, 0, stream>>>(pP, pP + (size_t)TOK_N*DMODEL, x, b_proj,
      ln2_g, ln2_b, h_hi, h_lo, out,
      w_rout, b_rout, w_noi, b_noi, w_skip, b_skip, noise, idx2, gate2, nskv);
  scan_kernel<<<1, blk, 0, stream>>>(idx2, gate2, nskv, tokb, gselb, zbuf, tsrc);
  // experts in groups of G: tconv -> up -> down(split-K 4) -> per-token gather
  int ngrp = NEXP / G;
  for (int grp=0; grp<ngrp; grp++){
    int e0 = grp*G;
    tconv_group<<<dim3(64,16,2*G), blk, 0, stream>>>(ew1, ew2, e1T, e2T, e0, G);
    mgemm<2,false><<<dim3(32,8,G), blk, 0, stream>>>(h_hi, nullptr, DMODEL,
        e1T, nullptr, DMODEL, eb1 + (size_t)e0*DFFD,
        nullptr, mid, nullptr, DFFD, DMODEL, tokb + e0*CAPMAX, (const __bf16*)zbuf);
    mgemm<4,false><<<dim3(8,8,4*G), blk, 0, stream>>>(mid, nullptr, DFFD,
        e2T, nullptr, DFFD, nullptr,
        yk, nullptr, nullptr, DMODEL, 1024, tokb + e0*CAPMAX, nullptr);
    gather_kernel<<<TOK_N, blk, 0, stream>>>(yk, tsrc, gselb, eb2, e0, G, out);
  }
}